// Round 4
// baseline (218.124 us; speedup 1.0000x reference)
//
#include <hip/hip_runtime.h>
#include <hip/hip_bf16.h>

#define C1 6.5025f      // (0.01*255)^2
#define C2 58.5225f     // (0.03*255)^2

// ---------------- Stage 1 ----------------
// 1536 WGs x 256 threads = 6144 waves, one wave per (b, bh, c, hgroup).
// Wave covers 8 rows x 512 w of one channel: lane loads float4 at w=4*lane
// and w=4*lane+256 for x and y (4 coalesced 1KB wave-loads per row).
// Depth-1 ping-pong prefetch keeps >=4 loads in flight, no barriers, no LDS.
// Per wave output: 32 (bw) x 5 partial sums = 160 floats into ws.
__global__ __launch_bounds__(256) void ssim_stage1(
    const float* __restrict__ x, const float* __restrict__ y,
    float* __restrict__ ws)
{
    const int tid  = threadIdx.x;
    const int lane = tid & 63;
    const int W    = blockIdx.x * 4 + (tid >> 6);   // 0..6143

    // W = ((b*32 + bh)*3 + c)*2 + hg
    const int hg = W & 1;
    const int t1 = W >> 1;
    const int c  = t1 % 3;
    const int br = t1 / 3;
    const int b  = br >> 5;
    const int bh = br & 31;
    const int h0 = bh * 16 + hg * 8;

    const size_t row0 = (((size_t)(b * 3 + c)) * 512 + (size_t)h0) * 512;
    const float* px = x + row0 + (size_t)(lane * 4);
    const float* py = y + row0 + (size_t)(lane * 4);

    float s0x = 0.f, s0y = 0.f, s0xx = 0.f, s0yy = 0.f, s0xy = 0.f; // w in [0,256)
    float s1x = 0.f, s1y = 0.f, s1xx = 0.f, s1yy = 0.f, s1xy = 0.f; // w in [256,512)

#define LOADR(XA, XB, YA, YB, r)                                   \
    XA = *reinterpret_cast<const float4*>(px + (r) * 512);         \
    XB = *reinterpret_cast<const float4*>(px + (r) * 512 + 256);   \
    YA = *reinterpret_cast<const float4*>(py + (r) * 512);         \
    YB = *reinterpret_cast<const float4*>(py + (r) * 512 + 256);

#define CONSUME(XA, XB, YA, YB)                                        \
    s0x += (XA.x + XA.y) + (XA.z + XA.w);                              \
    s0y += (YA.x + YA.y) + (YA.z + YA.w);                              \
    s0xx = fmaf(XA.x, XA.x, s0xx); s0xx = fmaf(XA.y, XA.y, s0xx);      \
    s0xx = fmaf(XA.z, XA.z, s0xx); s0xx = fmaf(XA.w, XA.w, s0xx);      \
    s0yy = fmaf(YA.x, YA.x, s0yy); s0yy = fmaf(YA.y, YA.y, s0yy);      \
    s0yy = fmaf(YA.z, YA.z, s0yy); s0yy = fmaf(YA.w, YA.w, s0yy);      \
    s0xy = fmaf(XA.x, YA.x, s0xy); s0xy = fmaf(XA.y, YA.y, s0xy);      \
    s0xy = fmaf(XA.z, YA.z, s0xy); s0xy = fmaf(XA.w, YA.w, s0xy);      \
    s1x += (XB.x + XB.y) + (XB.z + XB.w);                              \
    s1y += (YB.x + YB.y) + (YB.z + YB.w);                              \
    s1xx = fmaf(XB.x, XB.x, s1xx); s1xx = fmaf(XB.y, XB.y, s1xx);      \
    s1xx = fmaf(XB.z, XB.z, s1xx); s1xx = fmaf(XB.w, XB.w, s1xx);      \
    s1yy = fmaf(YB.x, YB.x, s1yy); s1yy = fmaf(YB.y, YB.y, s1yy);      \
    s1yy = fmaf(YB.z, YB.z, s1yy); s1yy = fmaf(YB.w, YB.w, s1yy);      \
    s1xy = fmaf(XB.x, YB.x, s1xy); s1xy = fmaf(XB.y, YB.y, s1xy);      \
    s1xy = fmaf(XB.z, YB.z, s1xy); s1xy = fmaf(XB.w, YB.w, s1xy);

    float4 xa0, xa1, ya0, ya1;   // ping
    float4 xb0, xb1, yb0, yb1;   // pong

    LOADR(xa0, xa1, ya0, ya1, 0)
    LOADR(xb0, xb1, yb0, yb1, 1)
    CONSUME(xa0, xa1, ya0, ya1)
    LOADR(xa0, xa1, ya0, ya1, 2)
    CONSUME(xb0, xb1, yb0, yb1)
    LOADR(xb0, xb1, yb0, yb1, 3)
    CONSUME(xa0, xa1, ya0, ya1)
    LOADR(xa0, xa1, ya0, ya1, 4)
    CONSUME(xb0, xb1, yb0, yb1)
    LOADR(xb0, xb1, yb0, yb1, 5)
    CONSUME(xa0, xa1, ya0, ya1)
    LOADR(xa0, xa1, ya0, ya1, 6)
    CONSUME(xb0, xb1, yb0, yb1)
    LOADR(xb0, xb1, yb0, yb1, 7)
    CONSUME(xa0, xa1, ya0, ya1)
    CONSUME(xb0, xb1, yb0, yb1)
#undef LOADR
#undef CONSUME

    // quad reduce (lanes sharing bw = lane>>2)
    #pragma unroll
    for (int d = 1; d < 4; d <<= 1) {
        s0x  += __shfl_xor(s0x,  d); s0y  += __shfl_xor(s0y,  d);
        s0xx += __shfl_xor(s0xx, d); s0yy += __shfl_xor(s0yy, d);
        s0xy += __shfl_xor(s0xy, d);
        s1x  += __shfl_xor(s1x,  d); s1y  += __shfl_xor(s1y,  d);
        s1xx += __shfl_xor(s1xx, d); s1yy += __shfl_xor(s1yy, d);
        s1xy += __shfl_xor(s1xy, d);
    }

    if ((lane & 3) == 0) {
        const int bw0 = lane >> 2;            // 0..15
        float* p0 = ws + (size_t)W * 160 + bw0 * 5;
        p0[0] = s0x; p0[1] = s0y; p0[2] = s0xx; p0[3] = s0yy; p0[4] = s0xy;
        float* p1 = p0 + 80;                  // bw = 16 + bw0
        p1[0] = s1x; p1[1] = s1y; p1[2] = s1xx; p1[3] = s1yy; p1[4] = s1xy;
    }
}

// ---------------- Stage 2 ----------------
// One WG per batch. Thread handles 4 blocks; each block sums its 6
// (c,hg) slices of 5 partials, computes SSIM; block-reduce 1024 SSIMs.
__global__ __launch_bounds__(256) void ssim_stage2(
    const float* __restrict__ ws, float* __restrict__ out)
{
    const int b   = blockIdx.x;
    const int tid = threadIdx.x;

    float acc = 0.f;
    #pragma unroll
    for (int k = 0; k < 4; ++k) {
        const int blk = tid * 4 + k;          // 0..1023
        const int bh  = blk >> 5;
        const int bw  = blk & 31;

        float Sx = 0.f, Sy = 0.f, Sxx = 0.f, Syy = 0.f, Sxy = 0.f;
        #pragma unroll
        for (int c = 0; c < 3; ++c) {
            #pragma unroll
            for (int hg = 0; hg < 2; ++hg) {
                const int W = ((b * 32 + bh) * 3 + c) * 2 + hg;
                const float* p = ws + (size_t)W * 160 + bw * 5;
                Sx += p[0]; Sy += p[1]; Sxx += p[2]; Syy += p[3]; Sxy += p[4];
            }
        }

        const float inv = 1.0f / 256.0f;      // ws*ws only (faithful to reference)
        const float mx  = Sx * inv;
        const float my  = Sy * inv;
        const float mx2 = mx * mx;
        const float my2 = my * my;
        const float vx  = Sxx * inv - mx2;
        const float vy  = Syy * inv - my2;
        const float cxy = Sxy * inv - mx * my;

        const float num = (2.0f * mx * my + C1) * (2.0f * cxy + C2);
        const float den = (mx2 + my2 + C1) * (vx + vy + C2);
        acc += num / den;
    }

    // reduce 256 partial sums
    #pragma unroll
    for (int d = 1; d < 64; d <<= 1) acc += __shfl_xor(acc, d);

    __shared__ float red[4];
    if ((tid & 63) == 0) red[tid >> 6] = acc;
    __syncthreads();
    if (tid == 0) {
        const float total = (red[0] + red[1]) + (red[2] + red[3]);
        out[b] = (1.0f - total * (1.0f / 1024.0f)) * 0.5f;
    }
}

extern "C" void kernel_launch(void* const* d_in, const int* in_sizes, int n_in,
                              void* d_out, int out_size, void* d_ws, size_t ws_size,
                              hipStream_t stream) {
    const float* x = (const float*)d_in[0];
    const float* y = (const float*)d_in[1];
    float* out = (float*)d_out;
    float* ws  = (float*)d_ws;   // 6144 * 160 floats = 3.93 MB

    ssim_stage1<<<1536, 256, 0, stream>>>(x, y, ws);
    ssim_stage2<<<32, 256, 0, stream>>>(ws, out);
}

// Round 6
// 198.933 us; speedup vs baseline: 1.0965x; 1.0965x over previous
//
#include <hip/hip_runtime.h>
#include <hip/hip_bf16.h>

#define C1 6.5025f      // (0.01*255)^2
#define C2 58.5225f     // (0.03*255)^2

typedef float vf4 __attribute__((ext_vector_type(4)));   // clang vector: NT-load legal

// ---------------- Stage 1 ----------------
// 1536 WGs x 256 threads = 6144 waves, one wave per (b, bh, c, hgroup).
// Wave covers 8 rows x 512 w of one channel. Depth-3 software pipeline
// (12 outstanding 1KB wave-loads) + non-temporal loads (skip L1 alloc).
__global__ __launch_bounds__(256) void ssim_stage1(
    const float* __restrict__ x, const float* __restrict__ y,
    float* __restrict__ ws)
{
    const int tid  = threadIdx.x;
    const int lane = tid & 63;
    const int W    = blockIdx.x * 4 + (tid >> 6);   // 0..6143

    // W = ((b*32 + bh)*3 + c)*2 + hg
    const int hg = W & 1;
    const int t1 = W >> 1;
    const int c  = t1 % 3;
    const int br = t1 / 3;
    const int b  = br >> 5;
    const int bh = br & 31;
    const int h0 = bh * 16 + hg * 8;

    const size_t row0 = (((size_t)(b * 3 + c)) * 512 + (size_t)h0) * 512;
    const float* px = x + row0 + (size_t)(lane * 4);
    const float* py = y + row0 + (size_t)(lane * 4);

    float s0x = 0.f, s0y = 0.f, s0xx = 0.f, s0yy = 0.f, s0xy = 0.f; // w in [0,256)
    float s1x = 0.f, s1y = 0.f, s1xx = 0.f, s1yy = 0.f, s1xy = 0.f; // w in [256,512)

#define NTL(p) __builtin_nontemporal_load(reinterpret_cast<const vf4*>(p))

#define LOADR(XA, XB, YA, YB, r)            \
    XA = NTL(px + (r) * 512);               \
    XB = NTL(px + (r) * 512 + 256);         \
    YA = NTL(py + (r) * 512);               \
    YB = NTL(py + (r) * 512 + 256);

#define CONSUME(XA, XB, YA, YB)                                                \
    s0x += (XA.x + XA.y) + (XA.z + XA.w);                                      \
    s0y += (YA.x + YA.y) + (YA.z + YA.w);                                      \
    s0xx = fmaf(XA.x, XA.x, s0xx); s0xx = fmaf(XA.y, XA.y, s0xx);              \
    s0xx = fmaf(XA.z, XA.z, s0xx); s0xx = fmaf(XA.w, XA.w, s0xx);              \
    s0yy = fmaf(YA.x, YA.x, s0yy); s0yy = fmaf(YA.y, YA.y, s0yy);              \
    s0yy = fmaf(YA.z, YA.z, s0yy); s0yy = fmaf(YA.w, YA.w, s0yy);              \
    s0xy = fmaf(XA.x, YA.x, s0xy); s0xy = fmaf(XA.y, YA.y, s0xy);              \
    s0xy = fmaf(XA.z, YA.z, s0xy); s0xy = fmaf(XA.w, YA.w, s0xy);              \
    s1x += (XB.x + XB.y) + (XB.z + XB.w);                                      \
    s1y += (YB.x + YB.y) + (YB.z + YB.w);                                      \
    s1xx = fmaf(XB.x, XB.x, s1xx); s1xx = fmaf(XB.y, XB.y, s1xx);              \
    s1xx = fmaf(XB.z, XB.z, s1xx); s1xx = fmaf(XB.w, XB.w, s1xx);              \
    s1yy = fmaf(YB.x, YB.x, s1yy); s1yy = fmaf(YB.y, YB.y, s1yy);              \
    s1yy = fmaf(YB.z, YB.z, s1yy); s1yy = fmaf(YB.w, YB.w, s1yy);              \
    s1xy = fmaf(XB.x, YB.x, s1xy); s1xy = fmaf(XB.y, YB.y, s1xy);              \
    s1xy = fmaf(XB.z, YB.z, s1xy); s1xy = fmaf(XB.w, YB.w, s1xy);

    vf4 xa0, xa1, ya0, ya1;   // stage A
    vf4 xb0, xb1, yb0, yb1;   // stage B
    vf4 xc0, xc1, yc0, yc1;   // stage C

    LOADR(xa0, xa1, ya0, ya1, 0)
    LOADR(xb0, xb1, yb0, yb1, 1)
    LOADR(xc0, xc1, yc0, yc1, 2)

    CONSUME(xa0, xa1, ya0, ya1)
    LOADR(xa0, xa1, ya0, ya1, 3)
    CONSUME(xb0, xb1, yb0, yb1)
    LOADR(xb0, xb1, yb0, yb1, 4)
    CONSUME(xc0, xc1, yc0, yc1)
    LOADR(xc0, xc1, yc0, yc1, 5)
    CONSUME(xa0, xa1, ya0, ya1)
    LOADR(xa0, xa1, ya0, ya1, 6)
    CONSUME(xb0, xb1, yb0, yb1)
    LOADR(xb0, xb1, yb0, yb1, 7)
    CONSUME(xc0, xc1, yc0, yc1)
    CONSUME(xa0, xa1, ya0, ya1)
    CONSUME(xb0, xb1, yb0, yb1)
#undef NTL
#undef LOADR
#undef CONSUME

    // quad reduce (lanes sharing bw = lane>>2)
    #pragma unroll
    for (int d = 1; d < 4; d <<= 1) {
        s0x  += __shfl_xor(s0x,  d); s0y  += __shfl_xor(s0y,  d);
        s0xx += __shfl_xor(s0xx, d); s0yy += __shfl_xor(s0yy, d);
        s0xy += __shfl_xor(s0xy, d);
        s1x  += __shfl_xor(s1x,  d); s1y  += __shfl_xor(s1y,  d);
        s1xx += __shfl_xor(s1xx, d); s1yy += __shfl_xor(s1yy, d);
        s1xy += __shfl_xor(s1xy, d);
    }

    if ((lane & 3) == 0) {
        const int bw0 = lane >> 2;            // 0..15
        float* p0 = ws + (size_t)W * 160 + bw0 * 5;
        p0[0] = s0x; p0[1] = s0y; p0[2] = s0xx; p0[3] = s0yy; p0[4] = s0xy;
        float* p1 = p0 + 80;                  // bw = 16 + bw0
        p1[0] = s1x; p1[1] = s1y; p1[2] = s1xx; p1[3] = s1yy; p1[4] = s1xy;
    }
}

// ---------------- Stage 2 ----------------
// One WG per batch. Thread handles 4 blocks; each block sums its 6
// (c,hg) slices of 5 partials, computes SSIM; block-reduce 1024 SSIMs.
__global__ __launch_bounds__(256) void ssim_stage2(
    const float* __restrict__ ws, float* __restrict__ out)
{
    const int b   = blockIdx.x;
    const int tid = threadIdx.x;

    float acc = 0.f;
    #pragma unroll
    for (int k = 0; k < 4; ++k) {
        const int blk = tid * 4 + k;          // 0..1023
        const int bh  = blk >> 5;
        const int bw  = blk & 31;

        float Sx = 0.f, Sy = 0.f, Sxx = 0.f, Syy = 0.f, Sxy = 0.f;
        #pragma unroll
        for (int c = 0; c < 3; ++c) {
            #pragma unroll
            for (int hg = 0; hg < 2; ++hg) {
                const int W = ((b * 32 + bh) * 3 + c) * 2 + hg;
                const float* p = ws + (size_t)W * 160 + bw * 5;
                Sx += p[0]; Sy += p[1]; Sxx += p[2]; Syy += p[3]; Sxy += p[4];
            }
        }

        const float inv = 1.0f / 256.0f;      // ws*ws only (faithful to reference)
        const float mx  = Sx * inv;
        const float my  = Sy * inv;
        const float mx2 = mx * mx;
        const float my2 = my * my;
        const float vx  = Sxx * inv - mx2;
        const float vy  = Syy * inv - my2;
        const float cxy = Sxy * inv - mx * my;

        const float num = (2.0f * mx * my + C1) * (2.0f * cxy + C2);
        const float den = (mx2 + my2 + C1) * (vx + vy + C2);
        acc += num / den;
    }

    // reduce 256 partial sums
    #pragma unroll
    for (int d = 1; d < 64; d <<= 1) acc += __shfl_xor(acc, d);

    __shared__ float red[4];
    if ((tid & 63) == 0) red[tid >> 6] = acc;
    __syncthreads();
    if (tid == 0) {
        const float total = (red[0] + red[1]) + (red[2] + red[3]);
        out[b] = (1.0f - total * (1.0f / 1024.0f)) * 0.5f;
    }
}

extern "C" void kernel_launch(void* const* d_in, const int* in_sizes, int n_in,
                              void* d_out, int out_size, void* d_ws, size_t ws_size,
                              hipStream_t stream) {
    const float* x = (const float*)d_in[0];
    const float* y = (const float*)d_in[1];
    float* out = (float*)d_out;
    float* ws  = (float*)d_ws;   // 6144 * 160 floats = 3.93 MB

    ssim_stage1<<<1536, 256, 0, stream>>>(x, y, ws);
    ssim_stage2<<<32, 256, 0, stream>>>(ws, out);
}

// Round 7
// 196.886 us; speedup vs baseline: 1.1079x; 1.0104x over previous
//
#include <hip/hip_runtime.h>
#include <hip/hip_bf16.h>

#define C1 6.5025f      // (0.01*255)^2
#define C2 58.5225f     // (0.03*255)^2

typedef float vf4 __attribute__((ext_vector_type(4)));   // clang vector: NT-load legal

// ---------------- Stage 1 ----------------
// 1536 WGs x 256 threads = 6144 waves, one wave per (b, bh, c, hgroup).
// Wave covers 8 rows x 512 w of one channel. Depth-4 software pipeline
// (16 outstanding 1KB wave-loads) + non-temporal loads (skip L1 alloc).
// VGPR target <=64 to keep 8 waves/SIMD.
__global__ __launch_bounds__(256) void ssim_stage1(
    const float* __restrict__ x, const float* __restrict__ y,
    float* __restrict__ ws)
{
    const int tid  = threadIdx.x;
    const int lane = tid & 63;
    const int W    = blockIdx.x * 4 + (tid >> 6);   // 0..6143

    // W = ((b*32 + bh)*3 + c)*2 + hg
    const int hg = W & 1;
    const int t1 = W >> 1;
    const int c  = t1 % 3;
    const int br = t1 / 3;
    const int b  = br >> 5;
    const int bh = br & 31;
    const int h0 = bh * 16 + hg * 8;

    const size_t row0 = (((size_t)(b * 3 + c)) * 512 + (size_t)h0) * 512;
    const float* px = x + row0 + (size_t)(lane * 4);
    const float* py = y + row0 + (size_t)(lane * 4);

    float s0x = 0.f, s0y = 0.f, s0xx = 0.f, s0yy = 0.f, s0xy = 0.f; // w in [0,256)
    float s1x = 0.f, s1y = 0.f, s1xx = 0.f, s1yy = 0.f, s1xy = 0.f; // w in [256,512)

#define NTL(p) __builtin_nontemporal_load(reinterpret_cast<const vf4*>(p))

#define LOADR(XA, XB, YA, YB, r)            \
    XA = NTL(px + (r) * 512);               \
    XB = NTL(px + (r) * 512 + 256);         \
    YA = NTL(py + (r) * 512);               \
    YB = NTL(py + (r) * 512 + 256);

#define CONSUME(XA, XB, YA, YB)                                                \
    s0x += (XA.x + XA.y) + (XA.z + XA.w);                                      \
    s0y += (YA.x + YA.y) + (YA.z + YA.w);                                      \
    s0xx = fmaf(XA.x, XA.x, s0xx); s0xx = fmaf(XA.y, XA.y, s0xx);              \
    s0xx = fmaf(XA.z, XA.z, s0xx); s0xx = fmaf(XA.w, XA.w, s0xx);              \
    s0yy = fmaf(YA.x, YA.x, s0yy); s0yy = fmaf(YA.y, YA.y, s0yy);              \
    s0yy = fmaf(YA.z, YA.z, s0yy); s0yy = fmaf(YA.w, YA.w, s0yy);              \
    s0xy = fmaf(XA.x, YA.x, s0xy); s0xy = fmaf(XA.y, YA.y, s0xy);              \
    s0xy = fmaf(XA.z, YA.z, s0xy); s0xy = fmaf(XA.w, YA.w, s0xy);              \
    s1x += (XB.x + XB.y) + (XB.z + XB.w);                                      \
    s1y += (YB.x + YB.y) + (YB.z + YB.w);                                      \
    s1xx = fmaf(XB.x, XB.x, s1xx); s1xx = fmaf(XB.y, XB.y, s1xx);              \
    s1xx = fmaf(XB.z, XB.z, s1xx); s1xx = fmaf(XB.w, XB.w, s1xx);              \
    s1yy = fmaf(YB.x, YB.x, s1yy); s1yy = fmaf(YB.y, YB.y, s1yy);              \
    s1yy = fmaf(YB.z, YB.z, s1yy); s1yy = fmaf(YB.w, YB.w, s1yy);              \
    s1xy = fmaf(XB.x, YB.x, s1xy); s1xy = fmaf(XB.y, YB.y, s1xy);              \
    s1xy = fmaf(XB.z, YB.z, s1xy); s1xy = fmaf(XB.w, YB.w, s1xy);

    vf4 xa0, xa1, ya0, ya1;   // stage A
    vf4 xb0, xb1, yb0, yb1;   // stage B
    vf4 xc0, xc1, yc0, yc1;   // stage C
    vf4 xd0, xd1, yd0, yd1;   // stage D

    LOADR(xa0, xa1, ya0, ya1, 0)
    LOADR(xb0, xb1, yb0, yb1, 1)
    LOADR(xc0, xc1, yc0, yc1, 2)
    LOADR(xd0, xd1, yd0, yd1, 3)

    CONSUME(xa0, xa1, ya0, ya1)
    LOADR(xa0, xa1, ya0, ya1, 4)
    CONSUME(xb0, xb1, yb0, yb1)
    LOADR(xb0, xb1, yb0, yb1, 5)
    CONSUME(xc0, xc1, yc0, yc1)
    LOADR(xc0, xc1, yc0, yc1, 6)
    CONSUME(xd0, xd1, yd0, yd1)
    LOADR(xd0, xd1, yd0, yd1, 7)
    CONSUME(xa0, xa1, ya0, ya1)
    CONSUME(xb0, xb1, yb0, yb1)
    CONSUME(xc0, xc1, yc0, yc1)
    CONSUME(xd0, xd1, yd0, yd1)
#undef NTL
#undef LOADR
#undef CONSUME

    // quad reduce (lanes sharing bw = lane>>2)
    #pragma unroll
    for (int d = 1; d < 4; d <<= 1) {
        s0x  += __shfl_xor(s0x,  d); s0y  += __shfl_xor(s0y,  d);
        s0xx += __shfl_xor(s0xx, d); s0yy += __shfl_xor(s0yy, d);
        s0xy += __shfl_xor(s0xy, d);
        s1x  += __shfl_xor(s1x,  d); s1y  += __shfl_xor(s1y,  d);
        s1xx += __shfl_xor(s1xx, d); s1yy += __shfl_xor(s1yy, d);
        s1xy += __shfl_xor(s1xy, d);
    }

    if ((lane & 3) == 0) {
        const int bw0 = lane >> 2;            // 0..15
        float* p0 = ws + (size_t)W * 160 + bw0 * 5;
        p0[0] = s0x; p0[1] = s0y; p0[2] = s0xx; p0[3] = s0yy; p0[4] = s0xy;
        float* p1 = p0 + 80;                  // bw = 16 + bw0
        p1[0] = s1x; p1[1] = s1y; p1[2] = s1xx; p1[3] = s1yy; p1[4] = s1xy;
    }
}

// ---------------- Stage 2 ----------------
// One WG per batch. Thread handles 4 blocks; each block sums its 6
// (c,hg) slices of 5 partials, computes SSIM; block-reduce 1024 SSIMs.
__global__ __launch_bounds__(256) void ssim_stage2(
    const float* __restrict__ ws, float* __restrict__ out)
{
    const int b   = blockIdx.x;
    const int tid = threadIdx.x;

    float acc = 0.f;
    #pragma unroll
    for (int k = 0; k < 4; ++k) {
        const int blk = tid * 4 + k;          // 0..1023
        const int bh  = blk >> 5;
        const int bw  = blk & 31;

        float Sx = 0.f, Sy = 0.f, Sxx = 0.f, Syy = 0.f, Sxy = 0.f;
        #pragma unroll
        for (int c = 0; c < 3; ++c) {
            #pragma unroll
            for (int hg = 0; hg < 2; ++hg) {
                const int W = ((b * 32 + bh) * 3 + c) * 2 + hg;
                const float* p = ws + (size_t)W * 160 + bw * 5;
                Sx += p[0]; Sy += p[1]; Sxx += p[2]; Syy += p[3]; Sxy += p[4];
            }
        }

        const float inv = 1.0f / 256.0f;      // ws*ws only (faithful to reference)
        const float mx  = Sx * inv;
        const float my  = Sy * inv;
        const float mx2 = mx * mx;
        const float my2 = my * my;
        const float vx  = Sxx * inv - mx2;
        const float vy  = Syy * inv - my2;
        const float cxy = Sxy * inv - mx * my;

        const float num = (2.0f * mx * my + C1) * (2.0f * cxy + C2);
        const float den = (mx2 + my2 + C1) * (vx + vy + C2);
        acc += num / den;
    }

    // reduce 256 partial sums
    #pragma unroll
    for (int d = 1; d < 64; d <<= 1) acc += __shfl_xor(acc, d);

    __shared__ float red[4];
    if ((tid & 63) == 0) red[tid >> 6] = acc;
    __syncthreads();
    if (tid == 0) {
        const float total = (red[0] + red[1]) + (red[2] + red[3]);
        out[b] = (1.0f - total * (1.0f / 1024.0f)) * 0.5f;
    }
}

extern "C" void kernel_launch(void* const* d_in, const int* in_sizes, int n_in,
                              void* d_out, int out_size, void* d_ws, size_t ws_size,
                              hipStream_t stream) {
    const float* x = (const float*)d_in[0];
    const float* y = (const float*)d_in[1];
    float* out = (float*)d_out;
    float* ws  = (float*)d_ws;   // 6144 * 160 floats = 3.93 MB

    ssim_stage1<<<1536, 256, 0, stream>>>(x, y, ws);
    ssim_stage2<<<32, 256, 0, stream>>>(ws, out);
}